// Round 1
// baseline (243.294 us; speedup 1.0000x reference)
//
#include <hip/hip_runtime.h>
#include <math.h>

// CTC batch cost, keras.backend.ctc_batch_cost semantics.
// B=256, T=512, C=256 (blank=255), L=128, S=2L+1=257.
//
// Design: one wave (64 lanes) per batch row. Lane i owns states 4i..4i+3
// (lane 63 also state 256). Forward recurrence kept in PROBABILITY domain
// (adds/muls only, no transcendentals); exact power-of-2 rescale every 8
// steps (butterfly max -> frexp/ldexp to 2^60, exponent accumulated in int).
// Gather of the ~129 needed channels per (b,t) is software-pipelined with a
// quad buffer (prefetch distance = 3 chunks of 8 timesteps).

namespace {
constexpr int Bn = 256;
constexpr int Tn = 512;
constexpr int Cn = 256;
constexpr int Ln = 128;
constexpr int U  = 8;           // timesteps per chunk
constexpr int NC = Tn / U;      // 64 chunks
constexpr float EPSf = 1e-7f;   // keras epsilon
constexpr float LN2f = 0.69314718055994530942f;
constexpr int   TGT  = 60;      // rescale target exponent
}

__global__ __launch_bounds__(64, 1)
void ctc_fwd(const int* __restrict__ y_true,
             const float* __restrict__ y_pred,
             float* __restrict__ out)
{
    const int b    = blockIdx.x;
    const int lane = threadIdx.x;   // 0..63, exactly one wave

    // --- labels and skip masks for this lane's states -------------------
    const int* yt = y_true + b * Ln;
    const int l0 = yt[2 * lane];                       // label for state 4i+1
    const int l1 = yt[2 * lane + 1];                   // label for state 4i+3
    const int lm = (lane > 0) ? yt[2 * lane - 1] : -1; // label for state 4i-1
    // skip (s-2 -> s) allowed iff s>=2 and labels differ (labels never blank)
    const float sk1 = (lane > 0 && l0 != lm) ? 1.0f : 0.0f; // state 4i+1
    const float sk3 = (l1 != l0) ? 1.0f : 0.0f;             // state 4i+3

    const float* __restrict__ base = y_pred + (size_t)b * Tn * Cn;

    // --- alpha state (prob domain). a0=1 on lane 0 makes the t=0 init
    // fall out of the uniform step formula (new_a0=(1+0)*Pb, new_a1=1*P0).
    float a0 = (lane == 0) ? 1.0f : 0.0f;
    float a1 = 0.0f, a2 = 0.0f, a3 = 0.0f, a4 = 0.0f;
    int Eacc = 0;   // true_alpha = stored_alpha * 2^Eacc

    // --- quad-buffered prefetch of (blank, label0, label1) probabilities
    float vb[4][U], v0[4][U], v1[4][U];

    auto load_chunk = [&](int c, float* bb, float* b0, float* b1) {
        const float* rp = base + (size_t)c * U * Cn;
        #pragma unroll
        for (int u = 0; u < U; ++u) {
            bb[u] = rp[u * Cn + (Cn - 1)];  // blank channel (wave-broadcast)
            b0[u] = rp[u * Cn + l0];
            b1[u] = rp[u * Cn + l1];
        }
    };

    auto compute_chunk = [&](const float* bb, const float* b0, const float* b1) {
        #pragma unroll
        for (int u = 0; u < U; ++u) {
            float n = __shfl_up(a3, 1);     // alpha[4i-1] from lane i-1
            if (lane == 0) n = 0.0f;
            const float Pb = bb[u] + EPSf;
            const float P0 = b0[u] + EPSf;
            const float P1 = b1[u] + EPSf;
            const float na0 = (a0 + n) * Pb;                   // even: no skip
            const float na1 = fmaf(sk1, n,  a1 + a0) * P0;     // odd + skip
            const float na2 = (a2 + a1) * Pb;
            const float na3 = fmaf(sk3, a1, a3 + a2) * P1;
            const float na4 = (a4 + a3) * Pb;                  // state 256 (lane 63)
            a0 = na0; a1 = na1; a2 = na2; a3 = na3; a4 = na4;
        }
        // exact wave-uniform rescale to keep max near 2^60
        float m = fmaxf(fmaxf(fmaxf(a0, a1), fmaxf(a2, a3)), a4);
        #pragma unroll
        for (int off = 32; off >= 1; off >>= 1)
            m = fmaxf(m, __shfl_xor(m, off));
        int e;
        (void)frexpf(m, &e);                // m = f * 2^e, f in [0.5,1)
        const int shift = TGT - e;
        a0 = ldexpf(a0, shift);
        a1 = ldexpf(a1, shift);
        a2 = ldexpf(a2, shift);
        a3 = ldexpf(a3, shift);
        a4 = ldexpf(a4, shift);
        Eacc -= shift;
    };

    load_chunk(0, vb[0], v0[0], v1[0]);
    load_chunk(1, vb[1], v0[1], v1[1]);
    load_chunk(2, vb[2], v0[2], v1[2]);

    for (int c = 0; c < NC; c += 4) {
        if (c + 3 < NC) load_chunk(c + 3, vb[3], v0[3], v1[3]);
        compute_chunk(vb[0], v0[0], v1[0]);
        if (c + 4 < NC) load_chunk(c + 4, vb[0], v0[0], v1[0]);
        compute_chunk(vb[1], v0[1], v1[1]);
        if (c + 5 < NC) load_chunk(c + 5, vb[1], v0[1], v1[1]);
        compute_chunk(vb[2], v0[2], v1[2]);
        if (c + 6 < NC) load_chunk(c + 6, vb[2], v0[2], v1[2]);
        compute_chunk(vb[3], v0[3], v1[3]);
    }

    // loss = -ln(alpha[S-1] + alpha[S-2]) ; states 255,256 = lane63 a3,a4
    if (lane == 63) {
        const float s = a3 + a4;
        out[b] = -LN2f * (log2f(s) + (float)Eacc);
    }
}

extern "C" void kernel_launch(void* const* d_in, const int* in_sizes, int n_in,
                              void* d_out, int out_size, void* d_ws, size_t ws_size,
                              hipStream_t stream) {
    const int*   y_true = (const int*)  d_in[0];   // [256,128] int32
    const float* y_pred = (const float*)d_in[1];   // [256,512,256] fp32
    float* out = (float*)d_out;                    // [256,1] fp32
    (void)in_sizes; (void)n_in; (void)out_size; (void)d_ws; (void)ws_size;
    ctc_fwd<<<dim3(Bn), dim3(64), 0, stream>>>(y_true, y_pred, out);
}

// Round 2
// 210.323 us; speedup vs baseline: 1.1568x; 1.1568x over previous
//
#include <hip/hip_runtime.h>
#include <math.h>

// CTC batch cost, keras.backend.ctc_batch_cost semantics.
// B=256, T=512, C=256 (blank=255), L=128, S=2L+1=257.
//
// Round 2 design: one wave per batch row (256 blocks x 64 threads).
//  * Whole 1KB probability row loaded per timestep with ONE coalesced
//    global_load_dwordx4 (inline asm so the compiler cannot sink it);
//    32-deep register pipeline, consumption gated by asm s_waitcnt vmcnt(31)
//    data-tied to the buffer. Prefetch depth 32 steps ~ 1900 cy >> HBM latency.
//  * Per-lane label channels gathered in-register via ds_bpermute
//    (channel ch lives in lane ch>>2 component ch&3); blank via readlane.
//  * Recurrence in probability domain (adds/fmas only); exact power-of-2
//    wave-uniform rescale every 8 steps (butterfly max -> frexp/ldexp).

namespace {
constexpr int Bn = 256;
constexpr int Tn = 512;
constexpr int Cn = 256;
constexpr int Ln = 128;
constexpr int D  = 32;          // pipeline depth (timesteps in flight)
constexpr float EPSf = 1e-7f;
constexpr float LN2f = 0.69314718055994530942f;
constexpr int   TGT  = 60;      // rescale target exponent
}

typedef float f4 __attribute__((ext_vector_type(4)));

#define GLOAD(dst, p) \
    asm volatile("global_load_dwordx4 %0, %1, off" : "=v"(dst) : "v"(p))
#define WAITP(dst) \
    asm volatile("s_waitcnt vmcnt(31)" : "+v"(dst))
#define WAIT0(dst) \
    asm volatile("s_waitcnt vmcnt(0)" : "+v"(dst))

__device__ __forceinline__ float bpf(int idx4, float v) {
    return __int_as_float(__builtin_amdgcn_ds_bpermute(idx4, __float_as_int(v)));
}

__global__ __launch_bounds__(64, 1)
void ctc_fwd(const int* __restrict__ y_true,
             const float* __restrict__ y_pred,
             float* __restrict__ out)
{
    const int b    = blockIdx.x;
    const int lane = threadIdx.x;   // 0..63, exactly one wave

    // --- labels & loop-invariant gather/skip constants -------------------
    const int* yt = y_true + b * Ln;
    const int l0 = yt[2 * lane];                        // state 4i+1 label
    const int l1 = yt[2 * lane + 1];                    // state 4i+3 label
    const int lm = (lane > 0) ? yt[2 * lane - 1] : -1;  // state 4i-1 label
    const float sk1 = (lane > 0 && l0 != lm) ? 1.0f : 0.0f;
    const float sk3 = (l1 != l0) ? 1.0f : 0.0f;
    const float lzm = (lane > 0) ? 1.0f : 0.0f;         // zero shfl_up @lane0

    const int i0 = (l0 >> 2) << 2;   // bpermute byte index: srclane*4
    const int i1 = (l1 >> 2) << 2;
    const bool s0a = l0 & 1, s0b = l0 & 2;
    const bool s1a = l1 & 1, s1b = l1 & 2;

    // --- alpha state (prob domain); a0=1@lane0 makes t=0 uniform ---------
    float a0 = (lane == 0) ? 1.0f : 0.0f;
    float a1 = 0.0f, a2 = 0.0f, a3 = 0.0f, a4 = 0.0f;
    int Eacc = 0;   // true_alpha = stored_alpha * 2^Eacc

    auto step = [&](f4 r) {
        // gather l0 / l1 channel probabilities from the wave's row registers
        float x0 = bpf(i0, r.x), x1 = bpf(i0, r.y);
        float x2 = bpf(i0, r.z), x3 = bpf(i0, r.w);
        float y0 = bpf(i1, r.x), y1 = bpf(i1, r.y);
        float y2 = bpf(i1, r.z), y3 = bpf(i1, r.w);
        float v0 = s0b ? (s0a ? x3 : x2) : (s0a ? x1 : x0);
        float v1 = s1b ? (s1a ? y3 : y2) : (s1a ? y1 : y0);
        float bb = __int_as_float(
            __builtin_amdgcn_readlane(__float_as_int(r.w), 63)); // ch 255

        float n  = __shfl_up(a3, 1) * lzm;   // alpha[4i-1]
        const float Pb = bb + EPSf;
        const float P0 = v0 + EPSf;
        const float P1 = v1 + EPSf;
        const float na0 = (a0 + n) * Pb;
        const float na1 = fmaf(sk1, n,  a1 + a0) * P0;
        const float na2 = (a2 + a1) * Pb;
        const float na3 = fmaf(sk3, a1, a3 + a2) * P1;
        const float na4 = (a4 + a3) * Pb;
        a0 = na0; a1 = na1; a2 = na2; a3 = na3; a4 = na4;
    };

    auto rescale = [&]() {
        float m = fmaxf(fmaxf(fmaxf(a0, a1), fmaxf(a2, a3)), a4);
        #pragma unroll
        for (int off = 32; off >= 1; off >>= 1)
            m = fmaxf(m, __shfl_xor(m, off));
        int e;
        (void)frexpf(m, &e);               // single v_frexp_exp
        const int shift = TGT - e;
        a0 = ldexpf(a0, shift);            // single v_ldexp each
        a1 = ldexpf(a1, shift);
        a2 = ldexpf(a2, shift);
        a3 = ldexpf(a3, shift);
        a4 = ldexpf(a4, shift);
        Eacc -= shift;
    };

    // --- pipelined main loop --------------------------------------------
    const float* p = y_pred + (size_t)b * Tn * Cn + lane * 4; // lane's 16B
    f4 buf[D];

    #pragma unroll
    for (int j = 0; j < D; ++j) { GLOAD(buf[j], p); p += Cn; }

    for (int c = 0; c < Tn - D; c += D) {     // 15 iterations
        #pragma unroll
        for (int j = 0; j < D; ++j) {
            WAITP(buf[j]);                    // oldest of 32 in flight done
            step(buf[j]);
            GLOAD(buf[j], p); p += Cn;        // refill: timestep c+D+j
            if ((j & 7) == 7) rescale();
        }
    }
    // epilogue: consume last D timesteps, nothing left to load
    #pragma unroll
    for (int j = 0; j < D; ++j) {
        WAIT0(buf[j]);                        // drains once, then no-op
        step(buf[j]);
        if ((j & 7) == 7) rescale();
    }

    // loss = -ln(alpha[S-1] + alpha[S-2]); states 255,256 = lane63 a3,a4
    if (lane == 63) {
        const float s = a3 + a4;
        out[b] = -LN2f * (log2f(s) + (float)Eacc);
    }
}

extern "C" void kernel_launch(void* const* d_in, const int* in_sizes, int n_in,
                              void* d_out, int out_size, void* d_ws, size_t ws_size,
                              hipStream_t stream) {
    const int*   y_true = (const int*)  d_in[0];   // [256,128] int32
    const float* y_pred = (const float*)d_in[1];   // [256,512,256] fp32
    float* out = (float*)d_out;                    // [256,1] fp32
    (void)in_sizes; (void)n_in; (void)out_size; (void)d_ws; (void)ws_size;
    ctc_fwd<<<dim3(Bn), dim3(64), 0, stream>>>(y_true, y_pred, out);
}

// Round 5
// 198.639 us; speedup vs baseline: 1.2248x; 1.0588x over previous
//
#include <hip/hip_runtime.h>
#include <math.h>

// CTC batch cost, keras.backend.ctc_batch_cost semantics.
// B=256, T=512, C=256 (blank=255), L=128, S=2L+1=257.
//
// Round 5: EXACT round-2-proven load skeleton (one wave per row; whole 1KB
// probability row per timestep via ONE coalesced inline-asm
// global_load_dwordx4; D=32 f4 buffers; s_waitcnt vmcnt(31) with a SINGLE
// tied f4 operand; drain epilogue). Only the gather changed: instead of
// 8 ds_bpermute + 6 cndmask per step (round 2's DS-latency trap), the row
// is staged through a 4-slot LDS ring (plain C++ stores/loads, compiler-
// managed lgkmcnt) and each lane reads its two loop-invariant label
// channels; compute runs one step behind the stage so LDS latency is
// covered by in-order issue. Blank channel via readlane (wave-uniform).
// Probability-domain recurrence; exact power-of-2 wave-uniform rescale
// every 16 steps (seed 2^100, target 2^100).

namespace {
constexpr int Bn = 256;
constexpr int Tn = 512;
constexpr int Cn = 256;
constexpr int Ln = 128;
constexpr int D  = 32;          // pipeline depth (timesteps in flight)
constexpr float EPSf = 1e-7f;
constexpr float LN2f = 0.69314718055994530942f;
constexpr int   TGT  = 100;     // rescale target exponent
}

typedef float f4 __attribute__((ext_vector_type(4)));

// round-2-proven forms, byte-identical
#define GLOAD(dst, p) \
    asm volatile("global_load_dwordx4 %0, %1, off" : "=v"(dst) : "v"(p))
#define WAITP(dst) \
    asm volatile("s_waitcnt vmcnt(31)" : "+v"(dst))
#define WAIT0(dst) \
    asm volatile("s_waitcnt vmcnt(0)" : "+v"(dst))

__device__ __forceinline__ float rdl63(float v) {
    return __int_as_float(__builtin_amdgcn_readlane(__float_as_int(v), 63));
}

__global__ __launch_bounds__(64, 1)
void ctc_fwd(const int* __restrict__ y_true,
             const float* __restrict__ y_pred,
             float* __restrict__ out)
{
    const int b    = blockIdx.x;
    const int lane = threadIdx.x;   // 0..63, exactly one wave

    __shared__ __align__(16) float lds[4 * Cn];   // 4-slot row ring (4 KB)

    // --- labels & loop-invariant constants -------------------------------
    const int* yt = y_true + b * Ln;
    const int l0 = yt[2 * lane];                        // state 4i+1 label
    const int l1 = yt[2 * lane + 1];                    // state 4i+3 label
    const int lm = (lane > 0) ? yt[2 * lane - 1] : -1;  // state 4i-1 label
    const float sk1 = (lane > 0 && l0 != lm) ? 1.0f : 0.0f;
    const float sk3 = (l1 != l0) ? 1.0f : 0.0f;
    const float lzm = (lane > 0) ? 1.0f : 0.0f;         // zero shfl_up @lane0

    // --- alpha state (prob domain); true_alpha = stored * 2^Eacc ----------
    float a0 = (lane == 0) ? 0x1p100f : 0.0f;
    float a1 = 0.0f, a2 = 0.0f, a3 = 0.0f, a4 = 0.0f;
    int Eacc = -100;

    auto step = [&](float rb, float r0, float r1) {
        float n = __shfl_up(a3, 1) * lzm;    // alpha[4i-1]
        const float Pb = rb + EPSf;
        const float P0 = r0 + EPSf;
        const float P1 = r1 + EPSf;
        const float na0 = (a0 + n) * Pb;
        const float na1 = fmaf(sk1, n,  a1 + a0) * P0;
        const float na2 = (a2 + a1) * Pb;
        const float na3 = fmaf(sk3, a1, a3 + a2) * P1;
        const float na4 = (a4 + a3) * Pb;
        a0 = na0; a1 = na1; a2 = na2; a3 = na3; a4 = na4;
    };

    auto rescale = [&]() {
        float m = fmaxf(fmaxf(fmaxf(a0, a1), fmaxf(a2, a3)), a4);
        #pragma unroll
        for (int off = 32; off >= 1; off >>= 1)
            m = fmaxf(m, __shfl_xor(m, off));
        int e;
        (void)frexpf(m, &e);
        const int shift = TGT - e;
        a0 = ldexpf(a0, shift);
        a1 = ldexpf(a1, shift);
        a2 = ldexpf(a2, shift);
        a3 = ldexpf(a3, shift);
        a4 = ldexpf(a4, shift);
        Eacc -= shift;
    };

    // --- warm-up: fill the pipeline (32 f4 loads in flight) ---------------
    const f4* p = (const f4*)(y_pred + (size_t)b * Tn * Cn) + lane;
    f4 buf[D];
    #pragma unroll
    for (int j = 0; j < D; ++j) { GLOAD(buf[j], p); p += Cn / 4; }

    float bold = 0.0f;          // blank prob of the step being computed

    // --- block 0 (steps 0..31 staged; steps 0..30 computed) ---------------
    #pragma unroll
    for (int j = 0; j < D; ++j) {
        WAITP(buf[j]);                                  // row j ready
        const float bnew = rdl63(buf[j].w);             // blank(j)
        float r0n = 0.0f, r1n = 0.0f;
        if (j >= 1) {                                   // P(l0),P(l1) @ step j-1
            r0n = lds[((j - 1) & 3) * Cn + l0];
            r1n = lds[((j - 1) & 3) * Cn + l1];
        }
        ((f4*)lds)[(j & 3) * (Cn / 4) + lane] = buf[j]; // stage row j
        GLOAD(buf[j], p); p += Cn / 4;                  // refill: row j+32
        if (j >= 1) step(bold, r0n, r1n);               // compute step j-1
        bold = bnew;
        if (j == 16) rescale();                         // after step 15
    }

    // --- main blocks (c = 32..448): compute steps c-1 .. c+30 --------------
    for (int c = D; c < Tn - D; c += D) {               // 14 blocks
        #pragma unroll
        for (int j = 0; j < D; ++j) {
            WAITP(buf[j]);                              // row c+j ready
            const float bnew = rdl63(buf[j].w);
            const float r0n = lds[((j - 1) & 3) * Cn + l0];
            const float r1n = lds[((j - 1) & 3) * Cn + l1];
            ((f4*)lds)[(j & 3) * (Cn / 4) + lane] = buf[j];
            GLOAD(buf[j], p); p += Cn / 4;              // refill: row c+j+32
            step(bold, r0n, r1n);                       // compute step c+j-1
            bold = bnew;
            if (j == 0 || j == 16) rescale();           // after steps ..15/..31
        }
    }

    // --- drain block (c = 480): no refills, rows 480..511 -----------------
    #pragma unroll
    for (int j = 0; j < D; ++j) {
        WAIT0(buf[j]);                                  // drains once @ j=0
        const float bnew = rdl63(buf[j].w);
        const float r0n = lds[((j - 1) & 3) * Cn + l0];
        const float r1n = lds[((j - 1) & 3) * Cn + l1];
        ((f4*)lds)[(j & 3) * (Cn / 4) + lane] = buf[j];
        step(bold, r0n, r1n);                           // compute step 479+j
        bold = bnew;
        if (j == 0 || j == 16) rescale();
    }

    // --- epilogue: compute step 511 (row staged at j=31, slot 3) -----------
    {
        const float r0n = lds[3 * Cn + l0];
        const float r1n = lds[3 * Cn + l1];
        step(bold, r0n, r1n);
    }

    // loss = -ln(alpha[S-1] + alpha[S-2]); states 255,256 = lane63 a3,a4
    if (lane == 63) {
        const float s = a3 + a4;
        out[b] = -LN2f * (log2f(s) + (float)Eacc);
    }
}

extern "C" void kernel_launch(void* const* d_in, const int* in_sizes, int n_in,
                              void* d_out, int out_size, void* d_ws, size_t ws_size,
                              hipStream_t stream) {
    const int*   y_true = (const int*)  d_in[0];   // [256,128] int32
    const float* y_pred = (const float*)d_in[1];   // [256,512,256] fp32
    float* out = (float*)d_out;                    // [256,1] fp32
    (void)in_sizes; (void)n_in; (void)out_size; (void)d_ws; (void)ws_size;
    ctc_fwd<<<dim3(Bn), dim3(64), 0, stream>>>(y_true, y_pred, out);
}

// Round 6
// 197.821 us; speedup vs baseline: 1.2299x; 1.0041x over previous
//
#include <hip/hip_runtime.h>
#include <math.h>

// CTC batch cost, keras.backend.ctc_batch_cost semantics.
// B=256, T=512, C=256 (blank=255), L=128, S=2L+1=257.
//
// Round 6: round-5 skeleton (one wave/row; whole 1KB row per step via ONE
// coalesced inline-asm global_load_dwordx4; D=32 f4 ring; vmcnt(31) gate;
// 4-slot LDS row ring) with the DS pipe taken OFF the critical path:
//  * recurrence neighbor exchange: DPP wave_shr:1 (VALU, ~5 cy) instead of
//    __shfl_up (ds_permute, ~120 cy measured single-wave latency).
//  * rescale reduction: 6-op DPP max-reduce (row_shr + row_bcast) instead
//    of 6 dependent ds_permute shfl_xor (~720 cy -> ~50 cy).
//  * LDS channel reads skewed one full iteration ahead of consumption
//    (stage row t, read channels of row t-1, compute step t-2), so the
//    ~120 cy ds_read latency is covered by an entire iteration.
// Probability-domain recurrence; exact power-of-2 wave-uniform rescale
// every 16 steps (seed 2^100, target 2^100) -- numerics as round 5.

namespace {
constexpr int Bn = 256;
constexpr int Tn = 512;
constexpr int Cn = 256;
constexpr int Ln = 128;
constexpr int D  = 32;          // pipeline depth (timesteps in flight)
constexpr float EPSf = 1e-7f;
constexpr float LN2f = 0.69314718055994530942f;
constexpr int   TGT  = 100;     // rescale target exponent
}

typedef float f4 __attribute__((ext_vector_type(4)));

// round-2/5-proven forms, byte-identical
#define GLOAD(dst, p) \
    asm volatile("global_load_dwordx4 %0, %1, off" : "=v"(dst) : "v"(p))
#define WAITP(dst) \
    asm volatile("s_waitcnt vmcnt(31)" : "+v"(dst))
#define WAIT0(dst) \
    asm volatile("s_waitcnt vmcnt(0)" : "+v"(dst))

__device__ __forceinline__ float rdl63(float v) {
    return __int_as_float(__builtin_amdgcn_readlane(__float_as_int(v), 63));
}
// lane i <- lane i-1 (lane 0 <- 0): DPP wave_shr:1, bound_ctrl=1
__device__ __forceinline__ float dpp_shr1(float v) {
    return __int_as_float(__builtin_amdgcn_update_dpp(
        0, __float_as_int(v), 0x138, 0xF, 0xF, true));
}
template <int CTRL>
__device__ __forceinline__ float dpp_max(float m) {
    float o = __int_as_float(__builtin_amdgcn_update_dpp(
        0, __float_as_int(m), CTRL, 0xF, 0xF, true));   // invalid lanes -> 0
    return fmaxf(m, o);                                  // values > 0, safe
}

__global__ __launch_bounds__(64, 1)
void ctc_fwd(const int* __restrict__ y_true,
             const float* __restrict__ y_pred,
             float* __restrict__ out)
{
    const int b    = blockIdx.x;
    const int lane = threadIdx.x;   // 0..63, exactly one wave

    __shared__ __align__(16) float lds[4 * Cn];   // 4-slot row ring (4 KB)

    // --- labels & loop-invariant constants -------------------------------
    const int* yt = y_true + b * Ln;
    const int l0 = yt[2 * lane];                        // state 4i+1 label
    const int l1 = yt[2 * lane + 1];                    // state 4i+3 label
    const int lm = (lane > 0) ? yt[2 * lane - 1] : -1;  // state 4i-1 label
    const float sk1 = (lane > 0 && l0 != lm) ? 1.0f : 0.0f;
    const float sk3 = (l1 != l0) ? 1.0f : 0.0f;

    // --- alpha state (prob domain); true_alpha = stored * 2^Eacc ----------
    float a0 = (lane == 0) ? 0x1p100f : 0.0f;
    float a1 = 0.0f, a2 = 0.0f, a3 = 0.0f, a4 = 0.0f;
    int Eacc = -100;

    auto step = [&](float rb, float r0, float r1) {
        const float n = dpp_shr1(a3);        // alpha[4i-1], VALU not DS
        const float Pb = rb + EPSf;
        const float P0 = r0 + EPSf;
        const float P1 = r1 + EPSf;
        const float na0 = (a0 + n) * Pb;
        const float na1 = fmaf(sk1, n,  a1 + a0) * P0;
        const float na2 = (a2 + a1) * Pb;
        const float na3 = fmaf(sk3, a1, a3 + a2) * P1;
        const float na4 = (a4 + a3) * Pb;
        a0 = na0; a1 = na1; a2 = na2; a3 = na3; a4 = na4;
    };

    auto rescale = [&]() {
        float m = fmaxf(fmaxf(fmaxf(a0, a1), fmaxf(a2, a3)), a4);
        m = dpp_max<0x111>(m);               // row_shr:1
        m = dpp_max<0x112>(m);               // row_shr:2
        m = dpp_max<0x114>(m);               // row_shr:4
        m = dpp_max<0x118>(m);               // row_shr:8
        m = dpp_max<0x142>(m);               // row_bcast:15
        m = dpp_max<0x143>(m);               // row_bcast:31 -> lane63 = wave max
        m = rdl63(m);                        // uniform
        int e;
        (void)frexpf(m, &e);
        const int shift = TGT - e;
        a0 = ldexpf(a0, shift);
        a1 = ldexpf(a1, shift);
        a2 = ldexpf(a2, shift);
        a3 = ldexpf(a3, shift);
        a4 = ldexpf(a4, shift);
        Eacc -= shift;
    };

    // --- warm-up: fill the pipeline (32 f4 loads in flight) ---------------
    const f4* p = (const f4*)(y_pred + (size_t)b * Tn * Cn) + lane;
    f4 buf[D];
    #pragma unroll
    for (int j = 0; j < D; ++j) { GLOAD(buf[j], p); p += Cn / 4; }

    // software-pipeline registers: compute runs 2 iterations behind staging
    float bq0 = 0.0f, bq1 = 0.0f;   // blank queue: bq0 = blank(step being computed)
    float r0c = 0.0f, r1c = 0.0f;   // channels (read last iteration)

    // --- block 0: rows 0..31 arrive; steps 0..29 computed ------------------
    #pragma unroll
    for (int j = 0; j < D; ++j) {
        WAITP(buf[j]);                                  // row j ready
        const float bnew = rdl63(buf[j].w);             // blank(j)
        float r0n = 0.0f, r1n = 0.0f;
        if (j >= 1) {                                   // channels of row j-1
            r0n = lds[((j - 1) & 3) * Cn + l0];
            r1n = lds[((j - 1) & 3) * Cn + l1];
        }
        ((f4*)lds)[(j & 3) * (Cn / 4) + lane] = buf[j]; // stage row j
        GLOAD(buf[j], p); p += Cn / 4;                  // refill: row j+32
        if (j >= 2) step(bq0, r0c, r1c);                // compute step j-2
        bq0 = bq1; bq1 = bnew; r0c = r0n; r1c = r1n;
        if (j == 17) rescale();                         // after step 15
    }

    // --- main blocks c=32..448: rows c..c+31; steps c-2..c+29 --------------
    for (int c = D; c < Tn - D; c += D) {               // 14 blocks
        #pragma unroll
        for (int j = 0; j < D; ++j) {
            WAITP(buf[j]);                              // row c+j ready
            const float bnew = rdl63(buf[j].w);
            const float r0n = lds[((j - 1) & 3) * Cn + l0];  // row c+j-1
            const float r1n = lds[((j - 1) & 3) * Cn + l1];
            ((f4*)lds)[(j & 3) * (Cn / 4) + lane] = buf[j];
            GLOAD(buf[j], p); p += Cn / 4;              // refill: row c+j+32
            step(bq0, r0c, r1c);                        // compute step c+j-2
            bq0 = bq1; bq1 = bnew; r0c = r0n; r1c = r1n;
            if (j == 1 || j == 17) rescale();           // after steps %16==15
        }
    }

    // --- drain block: rows 480..511, no refills; steps 478..509 ------------
    #pragma unroll
    for (int j = 0; j < D; ++j) {
        WAIT0(buf[j]);                                  // drains once @ j=0
        const float bnew = rdl63(buf[j].w);
        const float r0n = lds[((j - 1) & 3) * Cn + l0];
        const float r1n = lds[((j - 1) & 3) * Cn + l1];
        ((f4*)lds)[(j & 3) * (Cn / 4) + lane] = buf[j];
        step(bq0, r0c, r1c);                            // compute step 478+j
        bq0 = bq1; bq1 = bnew; r0c = r0n; r1c = r1n;
        if (j == 1 || j == 17) rescale();               // steps 479, 495
    }

    // --- epilogue: steps 510 and 511 ---------------------------------------
    {
        const float r0n = lds[3 * Cn + l0];             // channels row 511
        const float r1n = lds[3 * Cn + l1];
        step(bq0, r0c, r1c);                            // step 510
        bq0 = bq1; r0c = r0n; r1c = r1n;
        step(bq0, r0c, r1c);                            // step 511
    }

    // loss = -ln(alpha[S-1] + alpha[S-2]); states 255,256 = lane63 a3,a4
    if (lane == 63) {
        const float s = a3 + a4;
        out[b] = -LN2f * (log2f(s) + (float)Eacc);
    }
}

extern "C" void kernel_launch(void* const* d_in, const int* in_sizes, int n_in,
                              void* d_out, int out_size, void* d_ws, size_t ws_size,
                              hipStream_t stream) {
    const int*   y_true = (const int*)  d_in[0];   // [256,128] int32
    const float* y_pred = (const float*)d_in[1];   // [256,512,256] fp32
    float* out = (float*)d_out;                    // [256,1] fp32
    (void)in_sizes; (void)n_in; (void)out_size; (void)d_ws; (void)ws_size;
    ctc_fwd<<<dim3(Bn), dim3(64), 0, stream>>>(y_true, y_pred, out);
}

// Round 7
// 196.360 us; speedup vs baseline: 1.2390x; 1.0074x over previous
//
#include <hip/hip_runtime.h>
#include <math.h>

// CTC batch cost, keras.backend.ctc_batch_cost semantics.
// B=256, T=512, C=256 (blank=255), L=128, S=2L+1=257.
//
// Round 7: producer/consumer wave specialization. Round 6 showed a single
// wave sustains only ~2.7 B/cy/CU (per-wave MLP cap ~14 lines in flight,
// VALUBusy 4.6%) -- the 32-deep single-wave pipeline cannot go faster.
// New structure: 512 threads = 8 waves per block, 256 blocks (1/CU).
//   wave 0   : recurrence consumer (round-6 DPP machinery, proven exact:
//              DPP wave_shr:1 neighbor exchange, DPP max-reduce rescale,
//              prob-domain alpha with 2^100 seed / 2^100 target).
//   waves 1-7: loaders. Chunk = 32 rows (32 KB). Double-buffered 64-slot
//              LDS ring: during phase c, loaders fill chunk c+1 while the
//              consumer computes chunk c; one __syncthreads per phase.
//              Each loader: ~5 coalesced f4 row loads (proven asm form),
//              s_waitcnt vmcnt(0) (memory clobber, no reg ties), then
//              ds_write_b128 to the ring. 7 waves' MLP in parallel.
// Consumer reads P(l0),P(l1),P(blank) per step from LDS, skew-2 pipelined.

namespace {
constexpr int Bn = 256;
constexpr int Tn = 512;
constexpr int Cn = 256;
constexpr int Ln = 128;
constexpr int CH = 32;              // rows per chunk
constexpr int NCHUNK = Tn / CH;     // 16
constexpr int SLOTS = 64;           // LDS ring slots = 2 chunks (64 KB)
constexpr float EPSf = 1e-7f;
constexpr float LN2f = 0.69314718055994530942f;
constexpr int   TGT  = 100;         // rescale target exponent
}

typedef float f4 __attribute__((ext_vector_type(4)));

// proven load form: 64-bit VGPR address pair
#define GLOAD(dst, p) \
    asm volatile("global_load_dwordx4 %0, %1, off" : "=v"(dst) : "v"(p))
// full drain, memory clobber orders the subsequent LDS stores after it
#define VMWAIT0() \
    asm volatile("s_waitcnt vmcnt(0)" ::: "memory")

__device__ __forceinline__ float rdl63(float v) {
    return __int_as_float(__builtin_amdgcn_readlane(__float_as_int(v), 63));
}
// lane i <- lane i-1 (lane 0 <- 0): DPP wave_shr:1, bound_ctrl=1
__device__ __forceinline__ float dpp_shr1(float v) {
    return __int_as_float(__builtin_amdgcn_update_dpp(
        0, __float_as_int(v), 0x138, 0xF, 0xF, true));
}
template <int CTRL>
__device__ __forceinline__ float dpp_max(float m) {
    float o = __int_as_float(__builtin_amdgcn_update_dpp(
        0, __float_as_int(m), CTRL, 0xF, 0xF, true));   // invalid lanes -> 0
    return fmaxf(m, o);                                  // values >= 0, safe
}

__global__ __launch_bounds__(512, 1)
void ctc_fwd(const int* __restrict__ y_true,
             const float* __restrict__ y_pred,
             float* __restrict__ out)
{
    const int b    = blockIdx.x;
    const int tid  = (int)threadIdx.x;
    const int w    = tid >> 6;        // wave id 0..7
    const int lane = tid & 63;

    __shared__ __align__(16) float lds[SLOTS * Cn];   // 64 KB row ring

    const f4* gbase = (const f4*)(y_pred + (size_t)b * Tn * Cn);
    f4* ringv = (f4*)lds;

    // ---- loader: stage chunk ch (rows ch*32 .. ch*32+31) into the ring ----
    auto load_chunk = [&](int ch) {
        f4 tmp[5];
        int rows[5];
        #pragma unroll
        for (int k = 0; k < 5; ++k) {
            int rl = (w - 1) + 7 * k;              // 7 loader waves
            rl = rl > CH - 1 ? CH - 1 : rl;        // clamp: benign dup of row 31
            const int t = ch * CH + rl;
            rows[k] = t;
            GLOAD(tmp[k], gbase + (size_t)t * (Cn / 4) + lane);
        }
        VMWAIT0();
        #pragma unroll
        for (int k = 0; k < 5; ++k)
            ringv[(rows[k] & (SLOTS - 1)) * (Cn / 4) + lane] = tmp[k];
    };

    // ---- consumer state (wave 0 only uses it) -----------------------------
    const int* yt = y_true + b * Ln;
    const int l0 = yt[2 * lane];                        // state 4i+1 label
    const int l1 = yt[2 * lane + 1];                    // state 4i+3 label
    const int lm = (lane > 0) ? yt[2 * lane - 1] : -1;  // state 4i-1 label
    const float sk1 = (lane > 0 && l0 != lm) ? 1.0f : 0.0f;
    const float sk3 = (l1 != l0) ? 1.0f : 0.0f;

    float a0 = (lane == 0) ? 0x1p100f : 0.0f;   // true_alpha = stored * 2^Eacc
    float a1 = 0.0f, a2 = 0.0f, a3 = 0.0f, a4 = 0.0f;
    int Eacc = -100;

    auto step = [&](float rb, float r0, float r1) {
        const float n = dpp_shr1(a3);        // alpha[4i-1], VALU not DS
        const float Pb = rb + EPSf;
        const float P0 = r0 + EPSf;
        const float P1 = r1 + EPSf;
        const float na0 = (a0 + n) * Pb;
        const float na1 = fmaf(sk1, n,  a1 + a0) * P0;
        const float na2 = (a2 + a1) * Pb;
        const float na3 = fmaf(sk3, a1, a3 + a2) * P1;
        const float na4 = (a4 + a3) * Pb;
        a0 = na0; a1 = na1; a2 = na2; a3 = na3; a4 = na4;
    };

    auto rescale = [&]() {
        float m = fmaxf(fmaxf(fmaxf(a0, a1), fmaxf(a2, a3)), a4);
        m = dpp_max<0x111>(m);               // row_shr:1
        m = dpp_max<0x112>(m);               // row_shr:2
        m = dpp_max<0x114>(m);               // row_shr:4
        m = dpp_max<0x118>(m);               // row_shr:8
        m = dpp_max<0x142>(m);               // row_bcast:15
        m = dpp_max<0x143>(m);               // row_bcast:31
        m = rdl63(m);                        // wave-uniform max
        int e;
        (void)frexpf(m, &e);
        const int shift = TGT - e;
        a0 = ldexpf(a0, shift);
        a1 = ldexpf(a1, shift);
        a2 = ldexpf(a2, shift);
        a3 = ldexpf(a3, shift);
        a4 = ldexpf(a4, shift);
        Eacc -= shift;
    };

    // ---- consumer: run 32 steps of chunk c from the ring ------------------
    auto consume_chunk = [&](int c) {
        const int t0 = c * CH;
        // prime skew-2 pending registers (rows t0, t0+1)
        int s = (t0 & (SLOTS - 1)) * Cn;
        float rba = lds[s + (Cn - 1)], r0a = lds[s + l0], r1a = lds[s + l1];
        s = ((t0 + 1) & (SLOTS - 1)) * Cn;
        float rbb = lds[s + (Cn - 1)], r0b = lds[s + l0], r1b = lds[s + l1];
        #pragma unroll
        for (int j = 0; j < CH; ++j) {
            float rbn = 0.0f, r0n = 0.0f, r1n = 0.0f;
            if (j < CH - 2) {                // read row t0+j+2 (same chunk)
                const int ss = ((t0 + j + 2) & (SLOTS - 1)) * Cn;
                rbn = lds[ss + (Cn - 1)];
                r0n = lds[ss + l0];
                r1n = lds[ss + l1];
            }
            step(rba, r0a, r1a);             // step t0+j
            rba = rbb; r0a = r0b; r1a = r1b;
            rbb = rbn; r0b = r0n; r1b = r1n;
            if ((j & 15) == 15) rescale();   // every 16 steps
        }
    };

    // ---- phases -----------------------------------------------------------
    if (w > 0) load_chunk(0);
    __syncthreads();
    for (int c = 0; c < NCHUNK; ++c) {
        if (w > 0) {
            if (c + 1 < NCHUNK) load_chunk(c + 1);
        } else {
            consume_chunk(c);
        }
        __syncthreads();
    }

    // loss = -ln(alpha[S-1] + alpha[S-2]); states 255,256 = lane63 a3,a4
    if (w == 0 && lane == 63) {
        const float sfin = a3 + a4;
        out[b] = -LN2f * (log2f(sfin) + (float)Eacc);
    }
}

extern "C" void kernel_launch(void* const* d_in, const int* in_sizes, int n_in,
                              void* d_out, int out_size, void* d_ws, size_t ws_size,
                              hipStream_t stream) {
    const int*   y_true = (const int*)  d_in[0];   // [256,128] int32
    const float* y_pred = (const float*)d_in[1];   // [256,512,256] fp32
    float* out = (float*)d_out;                    // [256,1] fp32
    (void)in_sizes; (void)n_in; (void)out_size; (void)d_ws; (void)ws_size;
    ctc_fwd<<<dim3(Bn), dim3(512), 0, stream>>>(y_true, y_pred, out);
}